// Round 11
// baseline (210.483 us; speedup 1.0000x reference)
//
#include <hip/hip_runtime.h>
#include <math.h>

// ---------------- problem constants (fixed by setup_inputs) ----------------
#define B_    4
#define QN    32
#define KN    8192
#define HDIM  1024
#define NHD   16
#define DH    64
#define LCH   128
#define JCH   64

typedef float f32x4 __attribute__((ext_vector_type(4)));
typedef short s16x8 __attribute__((ext_vector_type(8)));
typedef unsigned short u16;

__device__ __forceinline__ u16 f2bf(float f) {          // round-to-nearest-even f32->bf16
  unsigned u = __float_as_uint(f);
  u += 0x7fffu + ((u >> 16) & 1u);
  return (u16)(u >> 16);
}

__device__ __forceinline__ void llds16(const void* g, void* l) {   // 16B global->LDS DMA
  __builtin_amdgcn_global_load_lds((const __attribute__((address_space(1))) unsigned int*)g,
                                   (__attribute__((address_space(3))) unsigned int*)l,
                                   16, 0, 0);
}

// ---------------- direct-write 64x64-tile GEMM over full K=1024, reg-prefetched ----------------
__device__ __forceinline__ void gemm64_direct(const float* __restrict__ A, const float* __restrict__ Bm,
                                              float* __restrict__ C, int m0, int n0, char* smem) {
  float (*As)[17] = (float(*)[17])smem;              // 64x17 = 4352 B
  float (*Bs)[64] = (float(*)[64])(smem + 4352);     // 16x64 = 4096 B
  int t = threadIdx.x;
  int tm = t >> 4, tn = t & 15;
  int ra = t >> 2, ka = (t & 3) * 4;
  int kb = t >> 4, nb = (t & 15) * 4;
  float c[4][4];
#pragma unroll
  for (int i = 0; i < 4; ++i)
#pragma unroll
    for (int j = 0; j < 4; ++j) c[i][j] = 0.f;
  float4 va = *(const float4*)(A + (size_t)(m0 + ra) * HDIM + ka);
  float4 vb = *(const float4*)(Bm + (size_t)kb * HDIM + n0 + nb);
  for (int kk = 0; kk < HDIM; kk += 16) {
    As[ra][ka] = va.x; As[ra][ka + 1] = va.y; As[ra][ka + 2] = va.z; As[ra][ka + 3] = va.w;
    *(float4*)&Bs[kb][nb] = vb;
    __syncthreads();
    if (kk + 16 < HDIM) {                 // prefetch next K-step under the FMA block
      va = *(const float4*)(A + (size_t)(m0 + ra) * HDIM + kk + 16 + ka);
      vb = *(const float4*)(Bm + (size_t)(kk + 16 + kb) * HDIM + n0 + nb);
    }
#pragma unroll
    for (int kq = 0; kq < 16; ++kq) {
      float a0 = As[tm * 4 + 0][kq], a1 = As[tm * 4 + 1][kq];
      float a2 = As[tm * 4 + 2][kq], a3 = As[tm * 4 + 3][kq];
      float b0 = Bs[kq][tn * 4 + 0], b1 = Bs[kq][tn * 4 + 1];
      float b2 = Bs[kq][tn * 4 + 2], b3 = Bs[kq][tn * 4 + 3];
      c[0][0] += a0 * b0; c[0][1] += a0 * b1; c[0][2] += a0 * b2; c[0][3] += a0 * b3;
      c[1][0] += a1 * b0; c[1][1] += a1 * b1; c[1][2] += a1 * b2; c[1][3] += a1 * b3;
      c[2][0] += a2 * b0; c[2][1] += a2 * b1; c[2][2] += a2 * b2; c[2][3] += a2 * b3;
      c[3][0] += a3 * b0; c[3][1] += a3 * b1; c[3][2] += a3 * b2; c[3][3] += a3 * b3;
    }
    __syncthreads();
  }
#pragma unroll
  for (int i = 0; i < 4; ++i)
#pragma unroll
    for (int j = 0; j < 4; ++j)
      C[(size_t)(m0 + tm * 4 + i) * HDIM + n0 + tn * 4 + j] = c[i][j];
}

// ---------------- k_front: qh GEMM | qvec LN | zero qpart  (69 blocks, own counters) ----------
__global__ __launch_bounds__(256) void k_front(const float* __restrict__ question,
                                               const float* __restrict__ Wq_g, const float* __restrict__ Wq_l,
                                               float* __restrict__ qh,
                                               const float* __restrict__ g, const float* __restrict__ lb,
                                               float* __restrict__ qvec, float* __restrict__ qpart) {
  __shared__ __align__(16) char smem[8448];
  int blk = blockIdx.x, t = threadIdx.x;
  if (blk < 64) {
    int s2 = blk >> 5, mt = (blk >> 4) & 1, ntile = blk & 15;
    gemm64_direct(question, s2 ? Wq_l : Wq_g, qh + (size_t)s2 * 131072, mt * 64, ntile * 64, smem);
  } else if (blk < 68) {
    int b = blk - 64;
    const float* p = question + (size_t)b * QN * HDIM + t * 4;
    float a0 = 0, a1 = 0, a2 = 0, a3 = 0;
    for (int r = 0; r < QN; ++r) {
      float4 v = *(const float4*)(p + (size_t)r * HDIM);
      a0 += v.x; a1 += v.y; a2 += v.z; a3 += v.w;
    }
    const float sc = 1.0f / QN;
    a0 *= sc; a1 *= sc; a2 *= sc; a3 *= sc;
    float s = a0 + a1 + a2 + a3;
    float ss = a0 * a0 + a1 * a1 + a2 * a2 + a3 * a3;
#pragma unroll
    for (int o = 1; o < 64; o <<= 1) { s += __shfl_xor(s, o, 64); ss += __shfl_xor(ss, o, 64); }
    float* sm = (float*)smem; float* sq = sm + 4;
    int wid = t >> 6, lane = t & 63;
    if (lane == 0) { sm[wid] = s; sq[wid] = ss; }
    __syncthreads();
    float S = sm[0] + sm[1] + sm[2] + sm[3], SS = sq[0] + sq[1] + sq[2] + sq[3];
    float mu = S / HDIM;
    float inv = rsqrtf(SS / HDIM - mu * mu + 1e-5f);
    int c = t * 4;
    float4 o;
    o.x = (a0 - mu) * inv * g[c + 0] + lb[c + 0];
    o.y = (a1 - mu) * inv * g[c + 1] + lb[c + 1];
    o.z = (a2 - mu) * inv * g[c + 2] + lb[c + 2];
    o.w = (a3 - mu) * inv * g[c + 3] + lb[c + 3];
    *(float4*)&qvec[(size_t)b * HDIM + c] = o;
  } else {
    float4 z = make_float4(0.f, 0.f, 0.f, 0.f);
#pragma unroll
    for (int i = 0; i < 4; ++i) ((float4*)qpart)[t * 4 + i] = z;
  }
}

// ---------------- k_cvtx: pure ctx fp32->bf16 + chunk column partials (1024 blocks) -----------
// 32 rows/block, 2 batches of 16 rows; 16 float4 loads in flight (forces ~72 VGPR MLP).
__global__ __launch_bounds__(256) void k_cvtx(const float* __restrict__ ctx, u16* __restrict__ ctxb,
                                              float* __restrict__ csum4) {
  int cb = blockIdx.x, t = threadIdx.x;
  int bj = cb >> 2, seg = cb & 3;
  const float* p = ctx + ((size_t)bj * LCH + seg * 32) * HDIM + t * 4;
  u16* op = ctxb + ((size_t)bj * LCH + seg * 32) * HDIM + t * 4;
  float a0 = 0, a1 = 0, a2 = 0, a3 = 0;
#pragma unroll
  for (int r0 = 0; r0 < 32; r0 += 16) {
    float4 v[16];
#pragma unroll
    for (int r = 0; r < 16; ++r) v[r] = *(const float4*)(p + (size_t)(r0 + r) * HDIM);
#pragma unroll
    for (int r = 0; r < 16; ++r) {
      ushort4 o;
      o.x = f2bf(v[r].x); o.y = f2bf(v[r].y); o.z = f2bf(v[r].z); o.w = f2bf(v[r].w);
      *(ushort4*)(op + (size_t)(r0 + r) * HDIM) = o;
      a0 += v[r].x; a1 += v[r].y; a2 += v[r].z; a3 += v[r].w;
    }
  }
  *(float4*)&csum4[((size_t)bj * 4 + seg) * HDIM + t * 4] = make_float4(a0, a1, a2, a3);
}

// ---------------- L2 (fat): afold | qpart split-K | cvec LN-finish | sbias ----------------
__global__ __launch_bounds__(256) void k_mid(const float* __restrict__ qh,
                                             const float* __restrict__ Wk_g, const float* __restrict__ Wk_l,
                                             const float* __restrict__ bq_g, const float* __restrict__ bq_l,
                                             u16* __restrict__ Ab,
                                             const float* __restrict__ bk_g, const float* __restrict__ bk_l,
                                             float* __restrict__ sbias,
                                             const float* __restrict__ qvec, const float* __restrict__ W1,
                                             float* __restrict__ qpart,
                                             const float* __restrict__ csum4,
                                             const float* __restrict__ g, const float* __restrict__ lb,
                                             float* __restrict__ cvec) {
  __shared__ __align__(16) char smem[8448];
  int blk = blockIdx.x, t = threadIdx.x;
  if (blk < 512) {
    // ---- afold: A[b][n][c] = (1/8)(qh+bq) . Wk  (bf16) ----
    int ct = blk & 3, slot = (blk >> 2) & 31, b = blk >> 7;
    int s2 = slot >> 4, h = slot & 15;
    const float* qhp = qh + (size_t)(s2 * 4 + b) * QN * HDIM;
    const float* Wk = s2 ? Wk_l : Wk_g;
    const float* bq = s2 ? bq_l : bq_g;
    float (*qs)[DH] = (float(*)[DH])smem;   // 32x64x4 = 8192 B
    {
      int q = t >> 3, doff = (t & 7) * 8;
      const float4* src = (const float4*)(qhp + (size_t)q * HDIM + h * DH + doff);
      float4 b0 = *(const float4*)(bq + h * DH + doff);
      float4 b1 = *(const float4*)(bq + h * DH + doff + 4);
      float4 v0 = src[0], v1 = src[1];
      qs[q][doff + 0] = v0.x + b0.x; qs[q][doff + 1] = v0.y + b0.y;
      qs[q][doff + 2] = v0.z + b0.z; qs[q][doff + 3] = v0.w + b0.w;
      qs[q][doff + 4] = v1.x + b1.x; qs[q][doff + 5] = v1.y + b1.y;
      qs[q][doff + 6] = v1.z + b1.z; qs[q][doff + 7] = v1.w + b1.w;
    }
    __syncthreads();
    int c = ct * 256 + t;
    float w[DH];
    const float* wr = Wk + (size_t)c * HDIM + h * DH;
#pragma unroll
    for (int d = 0; d < DH; d += 4) {
      float4 v = *(const float4*)(wr + d);
      w[d] = v.x; w[d + 1] = v.y; w[d + 2] = v.z; w[d + 3] = v.w;
    }
    u16* outp = Ab + ((size_t)b * HDIM + s2 * 512 + h * QN) * HDIM + c;
    for (int q = 0; q < QN; ++q) {
      float acc = 0.f;
#pragma unroll
      for (int d = 0; d < DH; ++d) acc += qs[q][d] * w[d];
      outp[(size_t)q * HDIM] = f2bf(acc * 0.125f);
    }
  } else if (blk < 768) {
    // ---- qpart split-K atomic ----
    int id = blk - 512;              // 0..255
    int nt = id & 3, b = (id >> 2) & 3, ks = id >> 4;
    int n = nt * 256 + t;
    const float* qv = qvec + (size_t)b * HDIM + ks * 64;
    const float* wp = W1 + (size_t)ks * 64 * HDIM + n;
    float acc = 0.f;
#pragma unroll 8
    for (int c = 0; c < 64; ++c) acc += qv[c] * wp[(size_t)c * HDIM];
    atomicAdd(&qpart[(size_t)b * HDIM + n], acc);
  } else if (blk < 1024) {
    // ---- cvec LN-finish from csum4 ----
    int bj = blk - 768;
    const float* cs = csum4 + (size_t)bj * 4 * HDIM + t * 4;
    float4 v0 = *(const float4*)(cs);
    float4 v1 = *(const float4*)(cs + HDIM);
    float4 v2 = *(const float4*)(cs + 2 * HDIM);
    float4 v3 = *(const float4*)(cs + 3 * HDIM);
    const float sc = 1.0f / LCH;
    float a0 = (v0.x + v1.x + v2.x + v3.x) * sc;
    float a1 = (v0.y + v1.y + v2.y + v3.y) * sc;
    float a2 = (v0.z + v1.z + v2.z + v3.z) * sc;
    float a3 = (v0.w + v1.w + v2.w + v3.w) * sc;
    float s = a0 + a1 + a2 + a3;
    float ss = a0 * a0 + a1 * a1 + a2 * a2 + a3 * a3;
#pragma unroll
    for (int o = 1; o < 64; o <<= 1) { s += __shfl_xor(s, o, 64); ss += __shfl_xor(ss, o, 64); }
    float* sm = (float*)smem; float* sq = sm + 4;
    int wid = t >> 6, lane = t & 63;
    if (lane == 0) { sm[wid] = s; sq[wid] = ss; }
    __syncthreads();
    float S = sm[0] + sm[1] + sm[2] + sm[3], SS = sq[0] + sq[1] + sq[2] + sq[3];
    float mu = S / HDIM;
    float inv = rsqrtf(SS / HDIM - mu * mu + 1e-5f);
    int c = t * 4;
    float4 o;
    o.x = (a0 - mu) * inv * g[c + 0] + lb[c + 0];
    o.y = (a1 - mu) * inv * g[c + 1] + lb[c + 1];
    o.z = (a2 - mu) * inv * g[c + 2] + lb[c + 2];
    o.w = (a3 - mu) * inv * g[c + 3] + lb[c + 3];
    *(float4*)&cvec[(size_t)bj * HDIM + c] = o;
  } else {
    // ---- sbias ----
    int i = (blk - 1024) * 256 + t;   // 0..4095
    int b = i >> 10, n = i & (HDIM - 1);
    int s2 = n >> 9, hq = n & 511, h = hq >> 5, q = hq & 31;
    const float* qr = qh + ((size_t)(s2 * 4 + b) * QN + q) * HDIM + h * DH;
    const float* bk = (s2 ? bk_l : bk_g) + h * DH;
    const float* bq = (s2 ? bq_l : bq_g) + h * DH;
    float acc = 0.f;
#pragma unroll
    for (int d = 0; d < DH; ++d) acc += (qr[d] + bq[d]) * bk[d];
    sbias[i] = acc * 0.125f;
  }
}

// ---------------- THE big fused kernel: S = ctx_bf16 @ A^T, column-wise (max,sumexp) per chunk ----
// 256x256 tile, BK=64, 8 waves (2M x 4N), 512 thr, dbuf 128KB, counted vmcnt(8) pipeline.
__global__ __launch_bounds__(512, 2) void k_scores(const u16* __restrict__ ctxb, const u16* __restrict__ Ab,
                                                   const float* __restrict__ sbias,
                                                   float* __restrict__ mglob, float* __restrict__ zglob,
                                                   float* __restrict__ locinv) {
  __shared__ u16 lds[65536];      // A0 | B0 | A1 | B1, 16384 u16 (32KB) each
  u16* A0 = lds;           u16* B0 = lds + 16384;
  u16* A1 = lds + 32768;   u16* B1 = lds + 49152;
  // XCD-bijective remap: 512 blocks, XCD x owns works [x*64, x*64+64)
  int bid = blockIdx.x;
  int work = (bid & 7) * 64 + (bid >> 3);
  int b = work >> 7, rem = work & 127, rt = rem >> 2, nt = rem & 3;
  int t = threadIdx.x, wid = t >> 6, lane = t & 63;
  int wm = wid >> 2, wn = wid & 3;
  int lrow = lane & 15, lkg = lane >> 4;

  const u16* ctx0 = ctxb + ((size_t)b * KN + rt * 256) * HDIM;
  const u16* Afp  = Ab + ((size_t)b * HDIM + nt * 256) * HDIM;

  int grow = wid * 8 + (lane >> 3);
  int gslot = (lane & 7) ^ (lane >> 3);
  const u16* gA[4]; const u16* gB[4]; int dof[4];
#pragma unroll
  for (int s = 0; s < 4; ++s) {
    gA[s] = ctx0 + (size_t)(s * 64 + grow) * HDIM + gslot * 8;
    gB[s] = Afp + (size_t)(s * 64 + grow) * HDIM + gslot * 8;
    dof[s] = s * 4096 + wid * 512;
  }

  int rowA = (wm * 128 + lrow) * 64;
  int rowB = (wn * 64 + lrow) * 64;
  int p8[2];
#pragma unroll
  for (int ks = 0; ks < 2; ++ks) p8[ks] = ((ks * 4 + lkg) ^ (lane & 7)) * 8;

  f32x4 acc[8][4];
#pragma unroll
  for (int mi = 0; mi < 8; ++mi)
#pragma unroll
    for (int ni = 0; ni < 4; ++ni) acc[mi][ni] = 0.f;

#define STAGE(AT, BT, KT) { \
  _Pragma("unroll") for (int s = 0; s < 4; ++s) { \
    llds16(gA[s] + (KT) * 64, (AT) + dof[s]); \
    llds16(gB[s] + (KT) * 64, (BT) + dof[s]); } }

#define COMPUTE(AT, BT) { \
  _Pragma("unroll") for (int ks = 0; ks < 2; ++ks) { \
    const u16* pA = (AT) + rowA + p8[ks]; \
    const u16* pB = (BT) + rowB + p8[ks]; \
    s16x8 av[8], bv[4]; \
    _Pragma("unroll") for (int mi = 0; mi < 8; ++mi) av[mi] = *(const s16x8*)(pA + mi * 1024); \
    _Pragma("unroll") for (int ni = 0; ni < 4; ++ni) bv[ni] = *(const s16x8*)(pB + ni * 1024); \
    _Pragma("unroll") for (int mi = 0; mi < 8; ++mi) \
    _Pragma("unroll") for (int ni = 0; ni < 4; ++ni) \
      acc[mi][ni] = __builtin_amdgcn_mfma_f32_16x16x32_bf16(av[mi], bv[ni], acc[mi][ni], 0, 0, 0); } }

#define SYNCN(N) { asm volatile("s_waitcnt vmcnt(" #N ")" ::: "memory"); \
                   __builtin_amdgcn_s_barrier(); \
                   __builtin_amdgcn_sched_barrier(0); }

#define SUB(KT, CA, CB, SA, SB, FULL) { \
  if (FULL) { STAGE(SA, SB, (KT) + 1); } \
  if (FULL) { SYNCN(8) } else { SYNCN(0) } \
  __builtin_amdgcn_s_setprio(1); \
  COMPUTE(CA, CB); \
  __builtin_amdgcn_s_setprio(0); \
  __builtin_amdgcn_s_barrier(); }

  STAGE(A0, B0, 0);
  SUB(0,  A0, B0, A1, B1, 1)
  SUB(1,  A1, B1, A0, B0, 1)
  SUB(2,  A0, B0, A1, B1, 1)
  SUB(3,  A1, B1, A0, B0, 1)
  SUB(4,  A0, B0, A1, B1, 1)
  SUB(5,  A1, B1, A0, B0, 1)
  SUB(6,  A0, B0, A1, B1, 1)
  SUB(7,  A1, B1, A0, B0, 1)
  SUB(8,  A0, B0, A1, B1, 1)
  SUB(9,  A1, B1, A0, B0, 1)
  SUB(10, A0, B0, A1, B1, 1)
  SUB(11, A1, B1, A0, B0, 1)
  SUB(12, A0, B0, A1, B1, 1)
  SUB(13, A1, B1, A0, B0, 1)
  SUB(14, A0, B0, A1, B1, 1)
  SUB(15, A1, B1, A0, B0, 0)
#undef STAGE
#undef COMPUTE
#undef SYNCN
#undef SUB

  // ---- epilogue: per column, (max, sumexp) over this wave's 128 rows (= one chunk) ----
  int jc = rt * 2 + wm;
  float sb[4];
#pragma unroll
  for (int ni = 0; ni < 4; ++ni)
    sb[ni] = sbias[b * HDIM + nt * 256 + wn * 64 + ni * 16 + lrow];
#pragma unroll
  for (int ni = 0; ni < 4; ++ni) {
    float m = -1e30f;
#pragma unroll
    for (int mi = 0; mi < 8; ++mi)
#pragma unroll
      for (int r = 0; r < 4; ++r) m = fmaxf(m, acc[mi][ni][r]);
    m += sb[ni];
    m = fmaxf(m, __shfl_xor(m, 16, 64));
    m = fmaxf(m, __shfl_xor(m, 32, 64));
    float z = 0.f;
#pragma unroll
    for (int mi = 0; mi < 8; ++mi)
#pragma unroll
      for (int r = 0; r < 4; ++r) z += __expf(acc[mi][ni][r] + sb[ni] - m);
    z += __shfl_xor(z, 16, 64);
    z += __shfl_xor(z, 32, 64);
    if (lane < 16) {
      int n = nt * 256 + wn * 64 + ni * 16 + lane;
      if (n < 512) {
        size_t o = ((size_t)b * 512 + n) * JCH + jc;
        mglob[o] = m; zglob[o] = z;
      } else {
        locinv[((size_t)b * JCH + jc) * 512 + (n - 512)] = 1.0f / z;
      }
    }
  }
}

// ---------------- L4 (fat): h1 GEMM | per-(b,hq) global max/denominator ----------------
__global__ __launch_bounds__(256) void k_post(const float* __restrict__ cvec, const float* __restrict__ W1,
                                              float* __restrict__ h1,
                                              const float* __restrict__ mglob, const float* __restrict__ zglob,
                                              float* __restrict__ Mh, float* __restrict__ Zr) {
  __shared__ __align__(16) char smem[8448];
  int blk = blockIdx.x, t = threadIdx.x;
  if (blk < 64) {
    int mt = blk >> 4, ntile = blk & 15;
    gemm64_direct(cvec, W1 + 1048576, h1, mt * 64, ntile * 64, smem);
  } else {
    int id = (blk - 64) * 256 + t;   // 0..2047
    int b = id >> 9, hq = id & 511;
    const float* mg = mglob + ((size_t)b * 512 + hq) * JCH;
    const float* zg = zglob + ((size_t)b * 512 + hq) * JCH;
    float m = -1e30f;
    for (int j = 0; j < JCH; ++j) m = fmaxf(m, mg[j]);
    float z = 0.f;
    for (int j = 0; j < JCH; ++j) z += zg[j] * __expf(mg[j] - m);
    Mh[id] = m;
    Zr[id] = 1.0f / z;
  }
}

// ---------------- per-(b,j) pooled scalars: att, loc, gate-dot (gelu fused) ----------------
__global__ __launch_bounds__(256) void k_chunk(const float* __restrict__ mglob, const float* __restrict__ zglob,
                                               const float* __restrict__ locinv,
                                               const float* __restrict__ Mh, const float* __restrict__ Zr,
                                               const float* __restrict__ h1, const float* __restrict__ qpart,
                                               const float* __restrict__ b1, const float* __restrict__ W2,
                                               float* __restrict__ abuf, float* __restrict__ lbuf,
                                               float* __restrict__ gbuf) {
  int bj = blockIdx.x, t = threadIdx.x;
  int b = bj >> 6, j = bj & 63;
  const float* mg = mglob + (size_t)b * 512 * JCH + j;   // stride JCH over hq
  const float* zg = zglob + (size_t)b * 512 * JCH + j;
  const float* lp = locinv + (size_t)bj * 512;
  const float* Mb = Mh + (size_t)b * 512;
  const float* Zb = Zr + (size_t)b * 512;
  float a = 0.f, l = 0.f, gsum = 0.f;
  for (int hq = t; hq < 512; hq += 256) {
    a += zg[(size_t)hq * JCH] * __expf(mg[(size_t)hq * JCH] - Mb[hq]) * Zb[hq];
    l += lp[hq];
  }
  const float* hp = h1 + (size_t)bj * HDIM;
  const float* qp = qpart + (size_t)b * HDIM;
  for (int n = t; n < HDIM; n += 256) {
    float x = hp[n] + qp[n] + b1[n];
    x = x * 0.5f * (1.0f + erff(x * 0.70710678118654752f));
    gsum += x * W2[n];
  }
#pragma unroll
  for (int o = 1; o < 64; o <<= 1) {
    a += __shfl_xor(a, o, 64); l += __shfl_xor(l, o, 64); gsum += __shfl_xor(gsum, o, 64);
  }
  __shared__ float ra[4], rl[4], rg[4];
  int wid = t >> 6, lane = t & 63;
  if (lane == 0) { ra[wid] = a; rl[wid] = l; rg[wid] = gsum; }
  __syncthreads();
  if (t == 0) {
    abuf[bj] = (ra[0] + ra[1] + ra[2] + ra[3]) * (1.0f / 65536.0f);
    lbuf[bj] = (rl[0] + rl[1] + rl[2] + rl[3]) * (1.0f / 512.0f);
    gbuf[bj] = rg[0] + rg[1] + rg[2] + rg[3];
  }
}

// ---------------- final: softmaxes over J, fuse, outputs ----------------
__global__ __launch_bounds__(64) void k_final(const float* __restrict__ abuf, const float* __restrict__ lbuf,
                                              const float* __restrict__ gbuf, const float* __restrict__ b2,
                                              float* __restrict__ out) {
  int b = blockIdx.x, t = threadIdx.x;   // 64 threads
  float a = abuf[b * 64 + t];
  float l = lbuf[b * 64 + t];
  float gt = gbuf[b * 64 + t] + b2[0];
  gt = 1.0f / (1.0f + __expf(-gt));
  float am = a, lm = l;
#pragma unroll
  for (int o = 1; o < 64; o <<= 1) { am = fmaxf(am, __shfl_xor(am, o, 64)); lm = fmaxf(lm, __shfl_xor(lm, o, 64)); }
  float ae = __expf(a - am), le = __expf(l - lm);
  float as_ = ae, ls_ = le;
#pragma unroll
  for (int o = 1; o < 64; o <<= 1) { as_ += __shfl_xor(as_, o, 64); ls_ += __shfl_xor(ls_, o, 64); }
  float gs = ae / as_, ls = le / ls_;
  float fu = gt * ls + (1.0f - gt) * gs;
  float fm = fu;
#pragma unroll
  for (int o = 1; o < 64; o <<= 1) fm = fmaxf(fm, __shfl_xor(fm, o, 64));
  float fe = __expf(fu - fm);
  float fs_ = fe;
#pragma unroll
  for (int o = 1; o < 64; o <<= 1) fs_ += __shfl_xor(fs_, o, 64);
  float fv = fe / fs_;
  out[b * 64 + t] = fv;
  out[256 + b * 64 + t] = ls;
  out[512 + b * 64 + t] = gs;
  float tot = fv;
#pragma unroll
  for (int o = 1; o < 64; o <<= 1) tot += __shfl_xor(tot, o, 64);
  if (t == 0) out[768 + b] = tot * (1.0f / 64.0f);
}

// ---------------- launcher ----------------
extern "C" void kernel_launch(void* const* d_in, const int* in_sizes, int n_in,
                              void* d_out, int out_size, void* d_ws, size_t ws_size,
                              hipStream_t stream) {
  const float* question = (const float*)d_in[0];
  const float* context  = (const float*)d_in[1];
  const float* Wq_l = (const float*)d_in[2];
  const float* bq_l = (const float*)d_in[3];
  const float* Wk_l = (const float*)d_in[4];
  const float* bk_l = (const float*)d_in[5];
  const float* Wq_g = (const float*)d_in[6];
  const float* bq_g = (const float*)d_in[7];
  const float* Wk_g = (const float*)d_in[8];
  const float* bk_g = (const float*)d_in[9];
  const float* ln_g = (const float*)d_in[10];
  const float* ln_b = (const float*)d_in[11];
  const float* W1   = (const float*)d_in[12];
  const float* b1   = (const float*)d_in[13];
  const float* W2   = (const float*)d_in[14];
  const float* b2   = (const float*)d_in[15];

  char* ws = (char*)d_ws;
  u16*   ctxb   = (u16*)(ws + 0);            // 67108864 B
  u16*   Ab     = (u16*)(ws + 67108864);     //  8388608 B
  float* qh     = (float*)(ws + 75497472);   //  1048576 B  [2][4][32][1024]
  float* sbias  = (float*)(ws + 76546048);   //    16384 B
  float* mglob  = (float*)(ws + 76562432);   //   524288 B  [4][512][64]  (transposed)
  float* zglob  = (float*)(ws + 77086720);   //   524288 B
  float* locinv = (float*)(ws + 77611008);   //   524288 B  [4][64][512]
  float* qvec   = (float*)(ws + 78135296);   //    16384 B
  float* cvec   = (float*)(ws + 78151680);   //  1048576 B  [256][1024]
  float* qpart  = (float*)(ws + 79200256);   //    16384 B
  float* h1     = (float*)(ws + 79216640);   //  1048576 B  [256][1024]
  float* Mh     = (float*)(ws + 80265216);   //     8192 B  [4][512]
  float* Zr     = (float*)(ws + 80273408);   //     8192 B
  float* abuf   = (float*)(ws + 80281600);   //     1024 B  [4][64]
  float* lbuf   = (float*)(ws + 80282624);   //     1024 B
  float* gbuf   = (float*)(ws + 80283648);   //     1024 B
  float* csum4  = (float*)(ws + 80284672);   //  4194304 B  [256][4][1024]

  hipLaunchKernelGGL(k_front, dim3(69), dim3(256), 0, stream,
                     question, Wq_g, Wq_l, qh, ln_g, ln_b, qvec, qpart);
  hipLaunchKernelGGL(k_cvtx, dim3(1024), dim3(256), 0, stream, context, ctxb, csum4);
  hipLaunchKernelGGL(k_mid, dim3(1040), dim3(256), 0, stream,
                     qh, Wk_g, Wk_l, bq_g, bq_l, Ab, bk_g, bk_l, sbias, qvec, W1, qpart,
                     csum4, ln_g, ln_b, cvec);
  hipLaunchKernelGGL(k_scores, dim3(512), dim3(512), 0, stream, ctxb, Ab, sbias, mglob, zglob, locinv);
  hipLaunchKernelGGL(k_post, dim3(72), dim3(256), 0, stream, cvec, W1, h1, mglob, zglob, Mh, Zr);
  hipLaunchKernelGGL(k_chunk, dim3(256), dim3(256), 0, stream, mglob, zglob, locinv, Mh, Zr, h1, qpart, b1, W2, abuf, lbuf, gbuf);
  hipLaunchKernelGGL(k_final, dim3(4), dim3(64), 0, stream, abuf, lbuf, gbuf, b2, (float*)d_out);
}

// Round 12
// 199.376 us; speedup vs baseline: 1.0557x; 1.0557x over previous
//
#include <hip/hip_runtime.h>
#include <math.h>

// ---------------- problem constants (fixed by setup_inputs) ----------------
#define B_    4
#define QN    32
#define KN    8192
#define HDIM  1024
#define NHD   16
#define DH    64
#define LCH   128
#define JCH   64

typedef float f32x4 __attribute__((ext_vector_type(4)));
typedef short s16x8 __attribute__((ext_vector_type(8)));
typedef unsigned short u16;

__device__ __forceinline__ u16 f2bf(float f) {          // round-to-nearest-even f32->bf16
  unsigned u = __float_as_uint(f);
  u += 0x7fffu + ((u >> 16) & 1u);
  return (u16)(u >> 16);
}

__device__ __forceinline__ float bf2f(u16 v) {
  return __uint_as_float(((unsigned)v) << 16);
}

__device__ __forceinline__ void llds16(const void* g, void* l) {   // 16B global->LDS DMA
  __builtin_amdgcn_global_load_lds((const __attribute__((address_space(1))) unsigned int*)g,
                                   (__attribute__((address_space(3))) unsigned int*)l,
                                   16, 0, 0);
}

// ---------------- direct-write 64x64-tile GEMM over full K=1024, reg-prefetched ----------------
__device__ __forceinline__ void gemm64_direct(const float* __restrict__ A, const float* __restrict__ Bm,
                                              float* __restrict__ C, int m0, int n0, char* smem) {
  float (*As)[17] = (float(*)[17])smem;              // 64x17 = 4352 B
  float (*Bs)[64] = (float(*)[64])(smem + 4352);     // 16x64 = 4096 B
  int t = threadIdx.x;
  int tm = t >> 4, tn = t & 15;
  int ra = t >> 2, ka = (t & 3) * 4;
  int kb = t >> 4, nb = (t & 15) * 4;
  float c[4][4];
#pragma unroll
  for (int i = 0; i < 4; ++i)
#pragma unroll
    for (int j = 0; j < 4; ++j) c[i][j] = 0.f;
  float4 va = *(const float4*)(A + (size_t)(m0 + ra) * HDIM + ka);
  float4 vb = *(const float4*)(Bm + (size_t)kb * HDIM + n0 + nb);
  for (int kk = 0; kk < HDIM; kk += 16) {
    As[ra][ka] = va.x; As[ra][ka + 1] = va.y; As[ra][ka + 2] = va.z; As[ra][ka + 3] = va.w;
    *(float4*)&Bs[kb][nb] = vb;
    __syncthreads();
    if (kk + 16 < HDIM) {                 // prefetch next K-step under the FMA block
      va = *(const float4*)(A + (size_t)(m0 + ra) * HDIM + kk + 16 + ka);
      vb = *(const float4*)(Bm + (size_t)(kk + 16 + kb) * HDIM + n0 + nb);
    }
#pragma unroll
    for (int kq = 0; kq < 16; ++kq) {
      float a0 = As[tm * 4 + 0][kq], a1 = As[tm * 4 + 1][kq];
      float a2 = As[tm * 4 + 2][kq], a3 = As[tm * 4 + 3][kq];
      float b0 = Bs[kq][tn * 4 + 0], b1 = Bs[kq][tn * 4 + 1];
      float b2 = Bs[kq][tn * 4 + 2], b3 = Bs[kq][tn * 4 + 3];
      c[0][0] += a0 * b0; c[0][1] += a0 * b1; c[0][2] += a0 * b2; c[0][3] += a0 * b3;
      c[1][0] += a1 * b0; c[1][1] += a1 * b1; c[1][2] += a1 * b2; c[1][3] += a1 * b3;
      c[2][0] += a2 * b0; c[2][1] += a2 * b1; c[2][2] += a2 * b2; c[2][3] += a2 * b3;
      c[3][0] += a3 * b0; c[3][1] += a3 * b1; c[3][2] += a3 * b2; c[3][3] += a3 * b3;
    }
    __syncthreads();
  }
#pragma unroll
  for (int i = 0; i < 4; ++i)
#pragma unroll
    for (int j = 0; j < 4; ++j)
      C[(size_t)(m0 + tm * 4 + i) * HDIM + n0 + tn * 4 + j] = c[i][j];
}

// ---------------- k_go: qh GEMM | qvec LN | zero qpart | grid-stride fp32->bf16 convert --------
// Convert role = m13-regime: 2048 blocks, VGPR-light, 1 load in flight/thread, max TLP.
__global__ __launch_bounds__(256) void k_go(const float* __restrict__ ctx, u16* __restrict__ ctxb,
                                            const float* __restrict__ question,
                                            const float* __restrict__ Wq_g, const float* __restrict__ Wq_l,
                                            float* __restrict__ qh,
                                            const float* __restrict__ g, const float* __restrict__ lb,
                                            float* __restrict__ qvec, float* __restrict__ qpart) {
  __shared__ __align__(16) char smem[8448];
  int blk = blockIdx.x, t = threadIdx.x;
  if (blk < 64) {
    int s2 = blk >> 5, mt = (blk >> 4) & 1, ntile = blk & 15;
    gemm64_direct(question, s2 ? Wq_l : Wq_g, qh + (size_t)s2 * 131072, mt * 64, ntile * 64, smem);
  } else if (blk < 68) {
    int b = blk - 64;
    const float* p = question + (size_t)b * QN * HDIM + t * 4;
    float a0 = 0, a1 = 0, a2 = 0, a3 = 0;
    for (int r = 0; r < QN; ++r) {
      float4 v = *(const float4*)(p + (size_t)r * HDIM);
      a0 += v.x; a1 += v.y; a2 += v.z; a3 += v.w;
    }
    const float sc = 1.0f / QN;
    a0 *= sc; a1 *= sc; a2 *= sc; a3 *= sc;
    float s = a0 + a1 + a2 + a3;
    float ss = a0 * a0 + a1 * a1 + a2 * a2 + a3 * a3;
#pragma unroll
    for (int o = 1; o < 64; o <<= 1) { s += __shfl_xor(s, o, 64); ss += __shfl_xor(ss, o, 64); }
    float* sm = (float*)smem; float* sq = sm + 4;
    int wid = t >> 6, lane = t & 63;
    if (lane == 0) { sm[wid] = s; sq[wid] = ss; }
    __syncthreads();
    float S = sm[0] + sm[1] + sm[2] + sm[3], SS = sq[0] + sq[1] + sq[2] + sq[3];
    float mu = S / HDIM;
    float inv = rsqrtf(SS / HDIM - mu * mu + 1e-5f);
    int c = t * 4;
    float4 o;
    o.x = (a0 - mu) * inv * g[c + 0] + lb[c + 0];
    o.y = (a1 - mu) * inv * g[c + 1] + lb[c + 1];
    o.z = (a2 - mu) * inv * g[c + 2] + lb[c + 2];
    o.w = (a3 - mu) * inv * g[c + 3] + lb[c + 3];
    *(float4*)&qvec[(size_t)b * HDIM + c] = o;
  } else if (blk == 68) {
    float4 z = make_float4(0.f, 0.f, 0.f, 0.f);
#pragma unroll
    for (int i = 0; i < 4; ++i) ((float4*)qpart)[t * 4 + i] = z;
  } else {
    // ---- pure grid-stride convert: 2048 blocks x 16 iters ----
    const int total4 = B_ * KN * HDIM / 4;     // 8388608 float4
    int idx = (blk - 69) * 256 + t;
    for (int i = idx; i < total4; i += 2048 * 256) {
      float4 v = ((const float4*)ctx)[i];
      ushort4 o;
      o.x = f2bf(v.x); o.y = f2bf(v.y); o.z = f2bf(v.z); o.w = f2bf(v.w);
      ((ushort4*)ctxb)[i] = o;
    }
  }
}

// ---------------- k_mid: afold | csum (bf16 column partials) | qpart split-K | sbias ----------
__global__ __launch_bounds__(256) void k_mid(const float* __restrict__ qh,
                                             const float* __restrict__ Wk_g, const float* __restrict__ Wk_l,
                                             const float* __restrict__ bq_g, const float* __restrict__ bq_l,
                                             u16* __restrict__ Ab,
                                             const float* __restrict__ bk_g, const float* __restrict__ bk_l,
                                             float* __restrict__ sbias,
                                             const float* __restrict__ qvec, const float* __restrict__ W1,
                                             float* __restrict__ qpart,
                                             const u16* __restrict__ ctxb, float* __restrict__ csum4) {
  __shared__ __align__(16) char smem[8448];
  int blk = blockIdx.x, t = threadIdx.x;
  if (blk < 512) {
    // ---- afold: A[b][n][c] = (1/8)(qh+bq) . Wk  (bf16) ----
    int ct = blk & 3, slot = (blk >> 2) & 31, b = blk >> 7;
    int s2 = slot >> 4, h = slot & 15;
    const float* qhp = qh + (size_t)(s2 * 4 + b) * QN * HDIM;
    const float* Wk = s2 ? Wk_l : Wk_g;
    const float* bq = s2 ? bq_l : bq_g;
    float (*qs)[DH] = (float(*)[DH])smem;   // 32x64x4 = 8192 B
    {
      int q = t >> 3, doff = (t & 7) * 8;
      const float4* src = (const float4*)(qhp + (size_t)q * HDIM + h * DH + doff);
      float4 b0 = *(const float4*)(bq + h * DH + doff);
      float4 b1 = *(const float4*)(bq + h * DH + doff + 4);
      float4 v0 = src[0], v1 = src[1];
      qs[q][doff + 0] = v0.x + b0.x; qs[q][doff + 1] = v0.y + b0.y;
      qs[q][doff + 2] = v0.z + b0.z; qs[q][doff + 3] = v0.w + b0.w;
      qs[q][doff + 4] = v1.x + b1.x; qs[q][doff + 5] = v1.y + b1.y;
      qs[q][doff + 6] = v1.z + b1.z; qs[q][doff + 7] = v1.w + b1.w;
    }
    __syncthreads();
    int c = ct * 256 + t;
    float w[DH];
    const float* wr = Wk + (size_t)c * HDIM + h * DH;
#pragma unroll
    for (int d = 0; d < DH; d += 4) {
      float4 v = *(const float4*)(wr + d);
      w[d] = v.x; w[d + 1] = v.y; w[d + 2] = v.z; w[d + 3] = v.w;
    }
    u16* outp = Ab + ((size_t)b * HDIM + s2 * 512 + h * QN) * HDIM + c;
    for (int q = 0; q < QN; ++q) {
      float acc = 0.f;
#pragma unroll
      for (int d = 0; d < DH; ++d) acc += qs[q][d] * w[d];
      outp[(size_t)q * HDIM] = f2bf(acc * 0.125f);
    }
  } else if (blk < 1536) {
    // ---- csum: column partial sums over 32 bf16 rows (VGPR-light, TLP) ----
    int cb = blk - 512;              // 0..1023
    int bj = cb >> 2, seg = cb & 3;
    const u16* p = ctxb + ((size_t)bj * LCH + seg * 32) * HDIM + t * 4;
    float a0 = 0, a1 = 0, a2 = 0, a3 = 0;
    for (int r = 0; r < 32; ++r) {
      ushort4 v = *(const ushort4*)(p + (size_t)r * HDIM);
      a0 += bf2f(v.x); a1 += bf2f(v.y); a2 += bf2f(v.z); a3 += bf2f(v.w);
    }
    *(float4*)&csum4[((size_t)bj * 4 + seg) * HDIM + t * 4] = make_float4(a0, a1, a2, a3);
  } else if (blk < 1792) {
    // ---- qpart split-K atomic ----
    int id = blk - 1536;             // 0..255
    int nt = id & 3, b = (id >> 2) & 3, ks = id >> 4;
    int n = nt * 256 + t;
    const float* qv = qvec + (size_t)b * HDIM + ks * 64;
    const float* wp = W1 + (size_t)ks * 64 * HDIM + n;
    float acc = 0.f;
#pragma unroll 8
    for (int c = 0; c < 64; ++c) acc += qv[c] * wp[(size_t)c * HDIM];
    atomicAdd(&qpart[(size_t)b * HDIM + n], acc);
  } else {
    // ---- sbias ----
    int i = (blk - 1792) * 256 + t;  // 0..4095
    int b = i >> 10, n = i & (HDIM - 1);
    int s2 = n >> 9, hq = n & 511, h = hq >> 5, q = hq & 31;
    const float* qr = qh + ((size_t)(s2 * 4 + b) * QN + q) * HDIM + h * DH;
    const float* bk = (s2 ? bk_l : bk_g) + h * DH;
    const float* bq = (s2 ? bq_l : bq_g) + h * DH;
    float acc = 0.f;
#pragma unroll
    for (int d = 0; d < DH; ++d) acc += (qr[d] + bq[d]) * bk[d];
    sbias[i] = acc * 0.125f;
  }
}

// ---------------- k_scores: MFMA blocks 0-511 | cvec LN-finish role blocks 512-639 -------------
// 256x256 tile, BK=64, 8 waves (2M x 4N), 512 thr, dbuf 128KB, counted vmcnt(8) pipeline.
__global__ __launch_bounds__(512, 2) void k_scores(const u16* __restrict__ ctxb, const u16* __restrict__ Ab,
                                                   const float* __restrict__ sbias,
                                                   float* __restrict__ mglob, float* __restrict__ zglob,
                                                   float* __restrict__ locinv,
                                                   const float* __restrict__ csum4,
                                                   const float* __restrict__ g, const float* __restrict__ lb,
                                                   float* __restrict__ cvec) {
  __shared__ u16 lds[65536];      // A0 | B0 | A1 | B1, 16384 u16 (32KB) each
  int bid = blockIdx.x;
  int t = threadIdx.x;
  if (bid >= 512) {
    // ---- cvec LN-finish: 128 blocks x 2 chunks (csum4 from k_mid; independent of MFMA data) ----
    int rb = bid - 512, half = t >> 8, tt = t & 255;
    int bj = rb * 2 + half;
    const float* cs = csum4 + (size_t)bj * 4 * HDIM + tt * 4;
    float4 v0 = *(const float4*)(cs);
    float4 v1 = *(const float4*)(cs + HDIM);
    float4 v2 = *(const float4*)(cs + 2 * HDIM);
    float4 v3 = *(const float4*)(cs + 3 * HDIM);
    const float sc = 1.0f / LCH;
    float a0 = (v0.x + v1.x + v2.x + v3.x) * sc;
    float a1 = (v0.y + v1.y + v2.y + v3.y) * sc;
    float a2 = (v0.z + v1.z + v2.z + v3.z) * sc;
    float a3 = (v0.w + v1.w + v2.w + v3.w) * sc;
    float s = a0 + a1 + a2 + a3;
    float ss = a0 * a0 + a1 * a1 + a2 * a2 + a3 * a3;
#pragma unroll
    for (int o = 1; o < 64; o <<= 1) { s += __shfl_xor(s, o, 64); ss += __shfl_xor(ss, o, 64); }
    float* smf = (float*)lds;
    int wid = t >> 6, lane = t & 63;
    if (lane == 0) { smf[wid] = s; smf[8 + wid] = ss; }
    __syncthreads();
    float S = smf[half * 4 + 0] + smf[half * 4 + 1] + smf[half * 4 + 2] + smf[half * 4 + 3];
    float SS = smf[8 + half * 4 + 0] + smf[8 + half * 4 + 1] + smf[8 + half * 4 + 2] + smf[8 + half * 4 + 3];
    float mu = S / HDIM;
    float inv = rsqrtf(SS / HDIM - mu * mu + 1e-5f);
    int c = tt * 4;
    float4 o;
    o.x = (a0 - mu) * inv * g[c + 0] + lb[c + 0];
    o.y = (a1 - mu) * inv * g[c + 1] + lb[c + 1];
    o.z = (a2 - mu) * inv * g[c + 2] + lb[c + 2];
    o.w = (a3 - mu) * inv * g[c + 3] + lb[c + 3];
    *(float4*)&cvec[(size_t)bj * HDIM + c] = o;
    return;
  }
  u16* A0 = lds;           u16* B0 = lds + 16384;
  u16* A1 = lds + 32768;   u16* B1 = lds + 49152;
  // XCD-bijective remap: 512 blocks, XCD x owns works [x*64, x*64+64)
  int work = (bid & 7) * 64 + (bid >> 3);
  int b = work >> 7, rem = work & 127, rt = rem >> 2, nt = rem & 3;
  int wid = t >> 6, lane = t & 63;
  int wm = wid >> 2, wn = wid & 3;
  int lrow = lane & 15, lkg = lane >> 4;

  const u16* ctx0 = ctxb + ((size_t)b * KN + rt * 256) * HDIM;
  const u16* Afp  = Ab + ((size_t)b * HDIM + nt * 256) * HDIM;

  int grow = wid * 8 + (lane >> 3);
  int gslot = (lane & 7) ^ (lane >> 3);
  const u16* gA[4]; const u16* gB[4]; int dof[4];
#pragma unroll
  for (int s = 0; s < 4; ++s) {
    gA[s] = ctx0 + (size_t)(s * 64 + grow) * HDIM + gslot * 8;
    gB[s] = Afp + (size_t)(s * 64 + grow) * HDIM + gslot * 8;
    dof[s] = s * 4096 + wid * 512;
  }

  int rowA = (wm * 128 + lrow) * 64;
  int rowB = (wn * 64 + lrow) * 64;
  int p8[2];
#pragma unroll
  for (int ks = 0; ks < 2; ++ks) p8[ks] = ((ks * 4 + lkg) ^ (lane & 7)) * 8;

  f32x4 acc[8][4];
#pragma unroll
  for (int mi = 0; mi < 8; ++mi)
#pragma unroll
    for (int ni = 0; ni < 4; ++ni) acc[mi][ni] = 0.f;

#define STAGE(AT, BT, KT) { \
  _Pragma("unroll") for (int s = 0; s < 4; ++s) { \
    llds16(gA[s] + (KT) * 64, (AT) + dof[s]); \
    llds16(gB[s] + (KT) * 64, (BT) + dof[s]); } }

#define COMPUTE(AT, BT) { \
  _Pragma("unroll") for (int ks = 0; ks < 2; ++ks) { \
    const u16* pA = (AT) + rowA + p8[ks]; \
    const u16* pB = (BT) + rowB + p8[ks]; \
    s16x8 av[8], bv[4]; \
    _Pragma("unroll") for (int mi = 0; mi < 8; ++mi) av[mi] = *(const s16x8*)(pA + mi * 1024); \
    _Pragma("unroll") for (int ni = 0; ni < 4; ++ni) bv[ni] = *(const s16x8*)(pB + ni * 1024); \
    _Pragma("unroll") for (int mi = 0; mi < 8; ++mi) \
    _Pragma("unroll") for (int ni = 0; ni < 4; ++ni) \
      acc[mi][ni] = __builtin_amdgcn_mfma_f32_16x16x32_bf16(av[mi], bv[ni], acc[mi][ni], 0, 0, 0); } }

#define SYNCN(N) { asm volatile("s_waitcnt vmcnt(" #N ")" ::: "memory"); \
                   __builtin_amdgcn_s_barrier(); \
                   __builtin_amdgcn_sched_barrier(0); }

#define SUB(KT, CA, CB, SA, SB, FULL) { \
  if (FULL) { STAGE(SA, SB, (KT) + 1); } \
  if (FULL) { SYNCN(8) } else { SYNCN(0) } \
  __builtin_amdgcn_s_setprio(1); \
  COMPUTE(CA, CB); \
  __builtin_amdgcn_s_setprio(0); \
  __builtin_amdgcn_s_barrier(); }

  STAGE(A0, B0, 0);
  SUB(0,  A0, B0, A1, B1, 1)
  SUB(1,  A1, B1, A0, B0, 1)
  SUB(2,  A0, B0, A1, B1, 1)
  SUB(3,  A1, B1, A0, B0, 1)
  SUB(4,  A0, B0, A1, B1, 1)
  SUB(5,  A1, B1, A0, B0, 1)
  SUB(6,  A0, B0, A1, B1, 1)
  SUB(7,  A1, B1, A0, B0, 1)
  SUB(8,  A0, B0, A1, B1, 1)
  SUB(9,  A1, B1, A0, B0, 1)
  SUB(10, A0, B0, A1, B1, 1)
  SUB(11, A1, B1, A0, B0, 1)
  SUB(12, A0, B0, A1, B1, 1)
  SUB(13, A1, B1, A0, B0, 1)
  SUB(14, A0, B0, A1, B1, 1)
  SUB(15, A1, B1, A0, B0, 0)
#undef STAGE
#undef COMPUTE
#undef SYNCN
#undef SUB

  // ---- epilogue: per column, (max, sumexp) over this wave's 128 rows (= one chunk) ----
  int jc = rt * 2 + wm;
  float sb[4];
#pragma unroll
  for (int ni = 0; ni < 4; ++ni)
    sb[ni] = sbias[b * HDIM + nt * 256 + wn * 64 + ni * 16 + lrow];
#pragma unroll
  for (int ni = 0; ni < 4; ++ni) {
    float m = -1e30f;
#pragma unroll
    for (int mi = 0; mi < 8; ++mi)
#pragma unroll
      for (int r = 0; r < 4; ++r) m = fmaxf(m, acc[mi][ni][r]);
    m += sb[ni];
    m = fmaxf(m, __shfl_xor(m, 16, 64));
    m = fmaxf(m, __shfl_xor(m, 32, 64));
    float z = 0.f;
#pragma unroll
    for (int mi = 0; mi < 8; ++mi)
#pragma unroll
      for (int r = 0; r < 4; ++r) z += __expf(acc[mi][ni][r] + sb[ni] - m);
    z += __shfl_xor(z, 16, 64);
    z += __shfl_xor(z, 32, 64);
    if (lane < 16) {
      int n = nt * 256 + wn * 64 + ni * 16 + lane;
      if (n < 512) {
        size_t o = ((size_t)b * 512 + n) * JCH + jc;
        mglob[o] = m; zglob[o] = z;
      } else {
        locinv[((size_t)b * JCH + jc) * 512 + (n - 512)] = 1.0f / z;
      }
    }
  }
}

// ---------------- k_post: h1 GEMM | per-(b,hq) global max/denominator ----------------
__global__ __launch_bounds__(256) void k_post(const float* __restrict__ cvec, const float* __restrict__ W1,
                                              float* __restrict__ h1,
                                              const float* __restrict__ mglob, const float* __restrict__ zglob,
                                              float* __restrict__ Mh, float* __restrict__ Zr) {
  __shared__ __align__(16) char smem[8448];
  int blk = blockIdx.x, t = threadIdx.x;
  if (blk < 64) {
    int mt = blk >> 4, ntile = blk & 15;
    gemm64_direct(cvec, W1 + 1048576, h1, mt * 64, ntile * 64, smem);
  } else {
    int id = (blk - 64) * 256 + t;   // 0..2047
    int b = id >> 9, hq = id & 511;
    const float* mg = mglob + ((size_t)b * 512 + hq) * JCH;
    const float* zg = zglob + ((size_t)b * 512 + hq) * JCH;
    float m = -1e30f;
    for (int j = 0; j < JCH; ++j) m = fmaxf(m, mg[j]);
    float z = 0.f;
    for (int j = 0; j < JCH; ++j) z += zg[j] * __expf(mg[j] - m);
    Mh[id] = m;
    Zr[id] = 1.0f / z;
  }
}

// ---------------- per-(b,j) pooled scalars: att, loc, gate-dot (gelu fused) ----------------
__global__ __launch_bounds__(256) void k_chunk(const float* __restrict__ mglob, const float* __restrict__ zglob,
                                               const float* __restrict__ locinv,
                                               const float* __restrict__ Mh, const float* __restrict__ Zr,
                                               const float* __restrict__ h1, const float* __restrict__ qpart,
                                               const float* __restrict__ b1, const float* __restrict__ W2,
                                               float* __restrict__ abuf, float* __restrict__ lbuf,
                                               float* __restrict__ gbuf) {
  int bj = blockIdx.x, t = threadIdx.x;
  int b = bj >> 6, j = bj & 63;
  const float* mg = mglob + (size_t)b * 512 * JCH + j;   // stride JCH over hq
  const float* zg = zglob + (size_t)b * 512 * JCH + j;
  const float* lp = locinv + (size_t)bj * 512;
  const float* Mb = Mh + (size_t)b * 512;
  const float* Zb = Zr + (size_t)b * 512;
  float a = 0.f, l = 0.f, gsum = 0.f;
  for (int hq = t; hq < 512; hq += 256) {
    a += zg[(size_t)hq * JCH] * __expf(mg[(size_t)hq * JCH] - Mb[hq]) * Zb[hq];
    l += lp[hq];
  }
  const float* hp = h1 + (size_t)bj * HDIM;
  const float* qp = qpart + (size_t)b * HDIM;
  for (int n = t; n < HDIM; n += 256) {
    float x = hp[n] + qp[n] + b1[n];
    x = x * 0.5f * (1.0f + erff(x * 0.70710678118654752f));
    gsum += x * W2[n];
  }
#pragma unroll
  for (int o = 1; o < 64; o <<= 1) {
    a += __shfl_xor(a, o, 64); l += __shfl_xor(l, o, 64); gsum += __shfl_xor(gsum, o, 64);
  }
  __shared__ float ra[4], rl[4], rg[4];
  int wid = t >> 6, lane = t & 63;
  if (lane == 0) { ra[wid] = a; rl[wid] = l; rg[wid] = gsum; }
  __syncthreads();
  if (t == 0) {
    abuf[bj] = (ra[0] + ra[1] + ra[2] + ra[3]) * (1.0f / 65536.0f);
    lbuf[bj] = (rl[0] + rl[1] + rl[2] + rl[3]) * (1.0f / 512.0f);
    gbuf[bj] = rg[0] + rg[1] + rg[2] + rg[3];
  }
}

// ---------------- final: softmaxes over J, fuse, outputs ----------------
__global__ __launch_bounds__(64) void k_final(const float* __restrict__ abuf, const float* __restrict__ lbuf,
                                              const float* __restrict__ gbuf, const float* __restrict__ b2,
                                              float* __restrict__ out) {
  int b = blockIdx.x, t = threadIdx.x;   // 64 threads
  float a = abuf[b * 64 + t];
  float l = lbuf[b * 64 + t];
  float gt = gbuf[b * 64 + t] + b2[0];
  gt = 1.0f / (1.0f + __expf(-gt));
  float am = a, lm = l;
#pragma unroll
  for (int o = 1; o < 64; o <<= 1) { am = fmaxf(am, __shfl_xor(am, o, 64)); lm = fmaxf(lm, __shfl_xor(lm, o, 64)); }
  float ae = __expf(a - am), le = __expf(l - lm);
  float as_ = ae, ls_ = le;
#pragma unroll
  for (int o = 1; o < 64; o <<= 1) { as_ += __shfl_xor(as_, o, 64); ls_ += __shfl_xor(ls_, o, 64); }
  float gs = ae / as_, ls = le / ls_;
  float fu = gt * ls + (1.0f - gt) * gs;
  float fm = fu;
#pragma unroll
  for (int o = 1; o < 64; o <<= 1) fm = fmaxf(fm, __shfl_xor(fm, o, 64));
  float fe = __expf(fu - fm);
  float fs_ = fe;
#pragma unroll
  for (int o = 1; o < 64; o <<= 1) fs_ += __shfl_xor(fs_, o, 64);
  float fv = fe / fs_;
  out[b * 64 + t] = fv;
  out[256 + b * 64 + t] = ls;
  out[512 + b * 64 + t] = gs;
  float tot = fv;
#pragma unroll
  for (int o = 1; o < 64; o <<= 1) tot += __shfl_xor(tot, o, 64);
  if (t == 0) out[768 + b] = tot * (1.0f / 64.0f);
}

// ---------------- launcher ----------------
extern "C" void kernel_launch(void* const* d_in, const int* in_sizes, int n_in,
                              void* d_out, int out_size, void* d_ws, size_t ws_size,
                              hipStream_t stream) {
  const float* question = (const float*)d_in[0];
  const float* context  = (const float*)d_in[1];
  const float* Wq_l = (const float*)d_in[2];
  const float* bq_l = (const float*)d_in[3];
  const float* Wk_l = (const float*)d_in[4];
  const float* bk_l = (const float*)d_in[5];
  const float* Wq_g = (const float*)d_in[6];
  const float* bq_g = (const float*)d_in[7];
  const float* Wk_g = (const float*)d_in[8];
  const float* bk_g = (const float*)d_in[9];
  const float* ln_g = (const float*)d_in[10];
  const float* ln_b = (const float*)d_in[11];
  const float* W1   = (const float*)d_in[12];
  const float* b1   = (const float*)d_in[13];
  const float* W2   = (const float*)d_in[14];
  const float* b2   = (const float*)d_in[15];

  char* ws = (char*)d_ws;
  u16*   ctxb   = (u16*)(ws + 0);            // 67108864 B
  u16*   Ab     = (u16*)(ws + 67108864);     //  8388608 B
  float* qh     = (float*)(ws + 75497472);   //  1048576 B  [2][4][32][1024]
  float* sbias  = (float*)(ws + 76546048);   //    16384 B
  float* mglob  = (float*)(ws + 76562432);   //   524288 B  [4][512][64]  (transposed)
  float* zglob  = (float*)(ws + 77086720);   //   524288 B
  float* locinv = (float*)(ws + 77611008);   //   524288 B  [4][64][512]
  float* qvec   = (float*)(ws + 78135296);   //    16384 B
  float* cvec   = (float*)(ws + 78151680);   //  1048576 B  [256][1024]
  float* qpart  = (float*)(ws + 79200256);   //    16384 B
  float* h1     = (float*)(ws + 79216640);   //  1048576 B  [256][1024]
  float* Mh     = (float*)(ws + 80265216);   //     8192 B  [4][512]
  float* Zr     = (float*)(ws + 80273408);   //     8192 B
  float* abuf   = (float*)(ws + 80281600);   //     1024 B  [4][64]
  float* lbuf   = (float*)(ws + 80282624);   //     1024 B
  float* gbuf   = (float*)(ws + 80283648);   //     1024 B
  float* csum4  = (float*)(ws + 80284672);   //  4194304 B  [256][4][1024]

  hipLaunchKernelGGL(k_go, dim3(2117), dim3(256), 0, stream,
                     context, ctxb, question, Wq_g, Wq_l, qh, ln_g, ln_b, qvec, qpart);
  hipLaunchKernelGGL(k_mid, dim3(1808), dim3(256), 0, stream,
                     qh, Wk_g, Wk_l, bq_g, bq_l, Ab, bk_g, bk_l, sbias, qvec, W1, qpart,
                     ctxb, csum4);
  hipLaunchKernelGGL(k_scores, dim3(640), dim3(512), 0, stream, ctxb, Ab, sbias, mglob, zglob, locinv,
                     csum4, ln_g, ln_b, cvec);
  hipLaunchKernelGGL(k_post, dim3(72), dim3(256), 0, stream, cvec, W1, h1, mglob, zglob, Mh, Zr);
  hipLaunchKernelGGL(k_chunk, dim3(256), dim3(256), 0, stream, mglob, zglob, locinv, Mh, Zr, h1, qpart, b1, W2, abuf, lbuf, gbuf);
  hipLaunchKernelGGL(k_final, dim3(4), dim3(64), 0, stream, abuf, lbuf, gbuf, b2, (float*)d_out);
}

// Round 13
// 197.537 us; speedup vs baseline: 1.0655x; 1.0093x over previous
//
#include <hip/hip_runtime.h>
#include <math.h>

// ---------------- problem constants (fixed by setup_inputs) ----------------
#define B_    4
#define QN    32
#define KN    8192
#define HDIM  1024
#define NHD   16
#define DH    64
#define LCH   128
#define JCH   64

typedef float f32x4 __attribute__((ext_vector_type(4)));
typedef short s16x8 __attribute__((ext_vector_type(8)));
typedef unsigned short u16;

__device__ __forceinline__ u16 f2bf(float f) {          // round-to-nearest-even f32->bf16
  unsigned u = __float_as_uint(f);
  u += 0x7fffu + ((u >> 16) & 1u);
  return (u16)(u >> 16);
}

__device__ __forceinline__ void llds16(const void* g, void* l) {   // 16B global->LDS DMA
  __builtin_amdgcn_global_load_lds((const __attribute__((address_space(1))) unsigned int*)g,
                                   (__attribute__((address_space(3))) unsigned int*)l,
                                   16, 0, 0);
}

// ---------------- direct-write 64x64-tile GEMM over full K=1024, reg-prefetched ----------------
__device__ __forceinline__ void gemm64_direct(const float* __restrict__ A, const float* __restrict__ Bm,
                                              float* __restrict__ C, int m0, int n0, char* smem) {
  float (*As)[17] = (float(*)[17])smem;              // 64x17 = 4352 B
  float (*Bs)[64] = (float(*)[64])(smem + 4352);     // 16x64 = 4096 B
  int t = threadIdx.x;
  int tm = t >> 4, tn = t & 15;
  int ra = t >> 2, ka = (t & 3) * 4;
  int kb = t >> 4, nb = (t & 15) * 4;
  float c[4][4];
#pragma unroll
  for (int i = 0; i < 4; ++i)
#pragma unroll
    for (int j = 0; j < 4; ++j) c[i][j] = 0.f;
  float4 va = *(const float4*)(A + (size_t)(m0 + ra) * HDIM + ka);
  float4 vb = *(const float4*)(Bm + (size_t)kb * HDIM + n0 + nb);
  for (int kk = 0; kk < HDIM; kk += 16) {
    As[ra][ka] = va.x; As[ra][ka + 1] = va.y; As[ra][ka + 2] = va.z; As[ra][ka + 3] = va.w;
    *(float4*)&Bs[kb][nb] = vb;
    __syncthreads();
    if (kk + 16 < HDIM) {                 // prefetch next K-step under the FMA block
      va = *(const float4*)(A + (size_t)(m0 + ra) * HDIM + kk + 16 + ka);
      vb = *(const float4*)(Bm + (size_t)(kk + 16 + kb) * HDIM + n0 + nb);
    }
#pragma unroll
    for (int kq = 0; kq < 16; ++kq) {
      float a0 = As[tm * 4 + 0][kq], a1 = As[tm * 4 + 1][kq];
      float a2 = As[tm * 4 + 2][kq], a3 = As[tm * 4 + 3][kq];
      float b0 = Bs[kq][tn * 4 + 0], b1 = Bs[kq][tn * 4 + 1];
      float b2 = Bs[kq][tn * 4 + 2], b3 = Bs[kq][tn * 4 + 3];
      c[0][0] += a0 * b0; c[0][1] += a0 * b1; c[0][2] += a0 * b2; c[0][3] += a0 * b3;
      c[1][0] += a1 * b0; c[1][1] += a1 * b1; c[1][2] += a1 * b2; c[1][3] += a1 * b3;
      c[2][0] += a2 * b0; c[2][1] += a2 * b1; c[2][2] += a2 * b2; c[2][3] += a2 * b3;
      c[3][0] += a3 * b0; c[3][1] += a3 * b1; c[3][2] += a3 * b2; c[3][3] += a3 * b3;
    }
    __syncthreads();
  }
#pragma unroll
  for (int i = 0; i < 4; ++i)
#pragma unroll
    for (int j = 0; j < 4; ++j)
      C[(size_t)(m0 + tm * 4 + i) * HDIM + n0 + tn * 4 + j] = c[i][j];
}

// ---------------- k_go: qh GEMM | qvec LN | zero qpart | convert+csum (16B stores) -------------
__global__ __launch_bounds__(256) void k_go(const float* __restrict__ ctx, u16* __restrict__ ctxb,
                                            float* __restrict__ csum4,
                                            const float* __restrict__ question,
                                            const float* __restrict__ Wq_g, const float* __restrict__ Wq_l,
                                            float* __restrict__ qh,
                                            const float* __restrict__ g, const float* __restrict__ lb,
                                            float* __restrict__ qvec, float* __restrict__ qpart) {
  __shared__ __align__(16) char smem[8448];
  int blk = blockIdx.x, t = threadIdx.x;
  if (blk < 64) {
    int s2 = blk >> 5, mt = (blk >> 4) & 1, ntile = blk & 15;
    gemm64_direct(question, s2 ? Wq_l : Wq_g, qh + (size_t)s2 * 131072, mt * 64, ntile * 64, smem);
  } else if (blk < 68) {
    int b = blk - 64;
    const float* p = question + (size_t)b * QN * HDIM + t * 4;
    float a0 = 0, a1 = 0, a2 = 0, a3 = 0;
    for (int r = 0; r < QN; ++r) {
      float4 v = *(const float4*)(p + (size_t)r * HDIM);
      a0 += v.x; a1 += v.y; a2 += v.z; a3 += v.w;
    }
    const float sc = 1.0f / QN;
    a0 *= sc; a1 *= sc; a2 *= sc; a3 *= sc;
    float s = a0 + a1 + a2 + a3;
    float ss = a0 * a0 + a1 * a1 + a2 * a2 + a3 * a3;
#pragma unroll
    for (int o = 1; o < 64; o <<= 1) { s += __shfl_xor(s, o, 64); ss += __shfl_xor(ss, o, 64); }
    float* sm = (float*)smem; float* sq = sm + 4;
    int wid = t >> 6, lane = t & 63;
    if (lane == 0) { sm[wid] = s; sq[wid] = ss; }
    __syncthreads();
    float S = sm[0] + sm[1] + sm[2] + sm[3], SS = sq[0] + sq[1] + sq[2] + sq[3];
    float mu = S / HDIM;
    float inv = rsqrtf(SS / HDIM - mu * mu + 1e-5f);
    int c = t * 4;
    float4 o;
    o.x = (a0 - mu) * inv * g[c + 0] + lb[c + 0];
    o.y = (a1 - mu) * inv * g[c + 1] + lb[c + 1];
    o.z = (a2 - mu) * inv * g[c + 2] + lb[c + 2];
    o.w = (a3 - mu) * inv * g[c + 3] + lb[c + 3];
    *(float4*)&qvec[(size_t)b * HDIM + c] = o;
  } else if (blk == 68) {
    float4 z = make_float4(0.f, 0.f, 0.f, 0.f);
#pragma unroll
    for (int i = 0; i < 4; ++i) ((float4*)qpart)[t * 4 + i] = z;
  } else {
    // ---- convert + csum: 1024 blocks x (32 rows of one chunk-quarter) ----
    // thread = (half = t>>7, cg = t&127): 16 rows x 8 cols; 32B loads, one 16B store/row.
    int cb = blk - 69;
    int bj = cb >> 2, seg = cb & 3;
    int cg = t & 127, half = t >> 7;
    const float* p = ctx + ((size_t)bj * LCH + seg * 32 + half * 16) * HDIM + cg * 8;
    u16* op = ctxb + ((size_t)bj * LCH + seg * 32 + half * 16) * HDIM + cg * 8;
    float cs0 = 0, cs1 = 0, cs2 = 0, cs3 = 0, cs4 = 0, cs5 = 0, cs6 = 0, cs7 = 0;
    float4 a0 = *(const float4*)(p);
    float4 b0 = *(const float4*)(p + 4);
#pragma unroll
    for (int r = 0; r < 16; ++r) {
      float4 a1, b1;
      if (r + 1 < 16) {
        a1 = *(const float4*)(p + (size_t)(r + 1) * HDIM);
        b1 = *(const float4*)(p + (size_t)(r + 1) * HDIM + 4);
      }
      s16x8 o;
      o[0] = (short)f2bf(a0.x); o[1] = (short)f2bf(a0.y); o[2] = (short)f2bf(a0.z); o[3] = (short)f2bf(a0.w);
      o[4] = (short)f2bf(b0.x); o[5] = (short)f2bf(b0.y); o[6] = (short)f2bf(b0.z); o[7] = (short)f2bf(b0.w);
      *(s16x8*)(op + (size_t)r * HDIM) = o;
      cs0 += a0.x; cs1 += a0.y; cs2 += a0.z; cs3 += a0.w;
      cs4 += b0.x; cs5 += b0.y; cs6 += b0.z; cs7 += b0.w;
      a0 = a1; b0 = b1;
    }
    float* red = (float*)smem;           // [2][1024]
    *(float4*)&red[half * 1024 + cg * 8] = make_float4(cs0, cs1, cs2, cs3);
    *(float4*)&red[half * 1024 + cg * 8 + 4] = make_float4(cs4, cs5, cs6, cs7);
    __syncthreads();
    if (t < 128) {
      float4 x0 = *(float4*)&red[t * 8],     y0 = *(float4*)&red[1024 + t * 8];
      float4 x1 = *(float4*)&red[t * 8 + 4], y1 = *(float4*)&red[1024 + t * 8 + 4];
      float* outp = &csum4[((size_t)bj * 4 + seg) * HDIM + t * 8];
      *(float4*)outp = make_float4(x0.x + y0.x, x0.y + y0.y, x0.z + y0.z, x0.w + y0.w);
      *(float4*)(outp + 4) = make_float4(x1.x + y1.x, x1.y + y1.y, x1.z + y1.z, x1.w + y1.w);
    }
  }
}

// ---------------- k_mid: afold | qpart split-K | sbias | cvec LN-finish ----------------
__global__ __launch_bounds__(256) void k_mid(const float* __restrict__ qh,
                                             const float* __restrict__ Wk_g, const float* __restrict__ Wk_l,
                                             const float* __restrict__ bq_g, const float* __restrict__ bq_l,
                                             u16* __restrict__ Ab,
                                             const float* __restrict__ bk_g, const float* __restrict__ bk_l,
                                             float* __restrict__ sbias,
                                             const float* __restrict__ qvec, const float* __restrict__ W1,
                                             float* __restrict__ qpart,
                                             const float* __restrict__ csum4,
                                             const float* __restrict__ g, const float* __restrict__ lb,
                                             float* __restrict__ cvec) {
  __shared__ __align__(16) char smem[8448];
  int blk = blockIdx.x, t = threadIdx.x;
  if (blk < 512) {
    // ---- afold: A[b][n][c] = (1/8)(qh+bq) . Wk  (bf16) ----
    int ct = blk & 3, slot = (blk >> 2) & 31, b = blk >> 7;
    int s2 = slot >> 4, h = slot & 15;
    const float* qhp = qh + (size_t)(s2 * 4 + b) * QN * HDIM;
    const float* Wk = s2 ? Wk_l : Wk_g;
    const float* bq = s2 ? bq_l : bq_g;
    float (*qs)[DH] = (float(*)[DH])smem;   // 32x64x4 = 8192 B
    {
      int q = t >> 3, doff = (t & 7) * 8;
      const float4* src = (const float4*)(qhp + (size_t)q * HDIM + h * DH + doff);
      float4 b0 = *(const float4*)(bq + h * DH + doff);
      float4 b1 = *(const float4*)(bq + h * DH + doff + 4);
      float4 v0 = src[0], v1 = src[1];
      qs[q][doff + 0] = v0.x + b0.x; qs[q][doff + 1] = v0.y + b0.y;
      qs[q][doff + 2] = v0.z + b0.z; qs[q][doff + 3] = v0.w + b0.w;
      qs[q][doff + 4] = v1.x + b1.x; qs[q][doff + 5] = v1.y + b1.y;
      qs[q][doff + 6] = v1.z + b1.z; qs[q][doff + 7] = v1.w + b1.w;
    }
    __syncthreads();
    int c = ct * 256 + t;
    float w[DH];
    const float* wr = Wk + (size_t)c * HDIM + h * DH;
#pragma unroll
    for (int d = 0; d < DH; d += 4) {
      float4 v = *(const float4*)(wr + d);
      w[d] = v.x; w[d + 1] = v.y; w[d + 2] = v.z; w[d + 3] = v.w;
    }
    u16* outp = Ab + ((size_t)b * HDIM + s2 * 512 + h * QN) * HDIM + c;
    for (int q = 0; q < QN; ++q) {
      float acc = 0.f;
#pragma unroll
      for (int d = 0; d < DH; ++d) acc += qs[q][d] * w[d];
      outp[(size_t)q * HDIM] = f2bf(acc * 0.125f);
    }
  } else if (blk < 768) {
    // ---- qpart split-K atomic ----
    int id = blk - 512;              // 0..255
    int nt = id & 3, b = (id >> 2) & 3, ks = id >> 4;
    int n = nt * 256 + t;
    const float* qv = qvec + (size_t)b * HDIM + ks * 64;
    const float* wp = W1 + (size_t)ks * 64 * HDIM + n;
    float acc = 0.f;
#pragma unroll 8
    for (int c = 0; c < 64; ++c) acc += qv[c] * wp[(size_t)c * HDIM];
    atomicAdd(&qpart[(size_t)b * HDIM + n], acc);
  } else if (blk < 784) {
    // ---- sbias ----
    int i = (blk - 768) * 256 + t;   // 0..4095
    int b = i >> 10, n = i & (HDIM - 1);
    int s2 = n >> 9, hq = n & 511, h = hq >> 5, q = hq & 31;
    const float* qr = qh + ((size_t)(s2 * 4 + b) * QN + q) * HDIM + h * DH;
    const float* bk = (s2 ? bk_l : bk_g) + h * DH;
    const float* bq = (s2 ? bq_l : bq_g) + h * DH;
    float acc = 0.f;
#pragma unroll
    for (int d = 0; d < DH; ++d) acc += (qr[d] + bq[d]) * bk[d];
    sbias[i] = acc * 0.125f;
  } else {
    // ---- cvec LN-finish from csum4 (256 blocks, one chunk each) ----
    int bj = blk - 784;
    const float* cs = csum4 + (size_t)bj * 4 * HDIM + t * 4;
    float4 v0 = *(const float4*)(cs);
    float4 v1 = *(const float4*)(cs + HDIM);
    float4 v2 = *(const float4*)(cs + 2 * HDIM);
    float4 v3 = *(const float4*)(cs + 3 * HDIM);
    const float sc = 1.0f / LCH;
    float a0 = (v0.x + v1.x + v2.x + v3.x) * sc;
    float a1 = (v0.y + v1.y + v2.y + v3.y) * sc;
    float a2 = (v0.z + v1.z + v2.z + v3.z) * sc;
    float a3 = (v0.w + v1.w + v2.w + v3.w) * sc;
    float s = a0 + a1 + a2 + a3;
    float ss = a0 * a0 + a1 * a1 + a2 * a2 + a3 * a3;
#pragma unroll
    for (int o = 1; o < 64; o <<= 1) { s += __shfl_xor(s, o, 64); ss += __shfl_xor(ss, o, 64); }
    float* sm = (float*)smem; float* sq = sm + 4;
    int wid = t >> 6, lane = t & 63;
    if (lane == 0) { sm[wid] = s; sq[wid] = ss; }
    __syncthreads();
    float S = sm[0] + sm[1] + sm[2] + sm[3], SS = sq[0] + sq[1] + sq[2] + sq[3];
    float mu = S / HDIM;
    float inv = rsqrtf(SS / HDIM - mu * mu + 1e-5f);
    int c = t * 4;
    float4 o;
    o.x = (a0 - mu) * inv * g[c + 0] + lb[c + 0];
    o.y = (a1 - mu) * inv * g[c + 1] + lb[c + 1];
    o.z = (a2 - mu) * inv * g[c + 2] + lb[c + 2];
    o.w = (a3 - mu) * inv * g[c + 3] + lb[c + 3];
    *(float4*)&cvec[(size_t)bj * HDIM + c] = o;
  }
}

// ---------------- THE big fused kernel: S = ctx_bf16 @ A^T, column-wise (max,sumexp) per chunk ----
// 256x256 tile, BK=64, 8 waves (2M x 4N), 512 thr, dbuf 128KB, counted vmcnt(8) pipeline.
__global__ __launch_bounds__(512, 2) void k_scores(const u16* __restrict__ ctxb, const u16* __restrict__ Ab,
                                                   const float* __restrict__ sbias,
                                                   float* __restrict__ mglob, float* __restrict__ zglob,
                                                   float* __restrict__ locinv) {
  __shared__ u16 lds[65536];      // A0 | B0 | A1 | B1, 16384 u16 (32KB) each
  u16* A0 = lds;           u16* B0 = lds + 16384;
  u16* A1 = lds + 32768;   u16* B1 = lds + 49152;
  // XCD-bijective remap: 512 blocks, XCD x owns works [x*64, x*64+64)
  int bid = blockIdx.x;
  int work = (bid & 7) * 64 + (bid >> 3);
  int b = work >> 7, rem = work & 127, rt = rem >> 2, nt = rem & 3;
  int t = threadIdx.x, wid = t >> 6, lane = t & 63;
  int wm = wid >> 2, wn = wid & 3;
  int lrow = lane & 15, lkg = lane >> 4;

  const u16* ctx0 = ctxb + ((size_t)b * KN + rt * 256) * HDIM;
  const u16* Afp  = Ab + ((size_t)b * HDIM + nt * 256) * HDIM;

  int grow = wid * 8 + (lane >> 3);
  int gslot = (lane & 7) ^ (lane >> 3);
  const u16* gA[4]; const u16* gB[4]; int dof[4];
#pragma unroll
  for (int s = 0; s < 4; ++s) {
    gA[s] = ctx0 + (size_t)(s * 64 + grow) * HDIM + gslot * 8;
    gB[s] = Afp + (size_t)(s * 64 + grow) * HDIM + gslot * 8;
    dof[s] = s * 4096 + wid * 512;
  }

  int rowA = (wm * 128 + lrow) * 64;
  int rowB = (wn * 64 + lrow) * 64;
  int p8[2];
#pragma unroll
  for (int ks = 0; ks < 2; ++ks) p8[ks] = ((ks * 4 + lkg) ^ (lane & 7)) * 8;

  f32x4 acc[8][4];
#pragma unroll
  for (int mi = 0; mi < 8; ++mi)
#pragma unroll
    for (int ni = 0; ni < 4; ++ni) acc[mi][ni] = 0.f;

#define STAGE(AT, BT, KT) { \
  _Pragma("unroll") for (int s = 0; s < 4; ++s) { \
    llds16(gA[s] + (KT) * 64, (AT) + dof[s]); \
    llds16(gB[s] + (KT) * 64, (BT) + dof[s]); } }

#define COMPUTE(AT, BT) { \
  _Pragma("unroll") for (int ks = 0; ks < 2; ++ks) { \
    const u16* pA = (AT) + rowA + p8[ks]; \
    const u16* pB = (BT) + rowB + p8[ks]; \
    s16x8 av[8], bv[4]; \
    _Pragma("unroll") for (int mi = 0; mi < 8; ++mi) av[mi] = *(const s16x8*)(pA + mi * 1024); \
    _Pragma("unroll") for (int ni = 0; ni < 4; ++ni) bv[ni] = *(const s16x8*)(pB + ni * 1024); \
    _Pragma("unroll") for (int mi = 0; mi < 8; ++mi) \
    _Pragma("unroll") for (int ni = 0; ni < 4; ++ni) \
      acc[mi][ni] = __builtin_amdgcn_mfma_f32_16x16x32_bf16(av[mi], bv[ni], acc[mi][ni], 0, 0, 0); } }

#define SYNCN(N) { asm volatile("s_waitcnt vmcnt(" #N ")" ::: "memory"); \
                   __builtin_amdgcn_s_barrier(); \
                   __builtin_amdgcn_sched_barrier(0); }

#define SUB(KT, CA, CB, SA, SB, FULL) { \
  if (FULL) { STAGE(SA, SB, (KT) + 1); } \
  if (FULL) { SYNCN(8) } else { SYNCN(0) } \
  __builtin_amdgcn_s_setprio(1); \
  COMPUTE(CA, CB); \
  __builtin_amdgcn_s_setprio(0); \
  __builtin_amdgcn_s_barrier(); }

  STAGE(A0, B0, 0);
  SUB(0,  A0, B0, A1, B1, 1)
  SUB(1,  A1, B1, A0, B0, 1)
  SUB(2,  A0, B0, A1, B1, 1)
  SUB(3,  A1, B1, A0, B0, 1)
  SUB(4,  A0, B0, A1, B1, 1)
  SUB(5,  A1, B1, A0, B0, 1)
  SUB(6,  A0, B0, A1, B1, 1)
  SUB(7,  A1, B1, A0, B0, 1)
  SUB(8,  A0, B0, A1, B1, 1)
  SUB(9,  A1, B1, A0, B0, 1)
  SUB(10, A0, B0, A1, B1, 1)
  SUB(11, A1, B1, A0, B0, 1)
  SUB(12, A0, B0, A1, B1, 1)
  SUB(13, A1, B1, A0, B0, 1)
  SUB(14, A0, B0, A1, B1, 1)
  SUB(15, A1, B1, A0, B0, 0)
#undef STAGE
#undef COMPUTE
#undef SYNCN
#undef SUB

  // ---- epilogue: per column, (max, sumexp) over this wave's 128 rows (= one chunk) ----
  int jc = rt * 2 + wm;
  float sb[4];
#pragma unroll
  for (int ni = 0; ni < 4; ++ni)
    sb[ni] = sbias[b * HDIM + nt * 256 + wn * 64 + ni * 16 + lrow];
#pragma unroll
  for (int ni = 0; ni < 4; ++ni) {
    float m = -1e30f;
#pragma unroll
    for (int mi = 0; mi < 8; ++mi)
#pragma unroll
      for (int r = 0; r < 4; ++r) m = fmaxf(m, acc[mi][ni][r]);
    m += sb[ni];
    m = fmaxf(m, __shfl_xor(m, 16, 64));
    m = fmaxf(m, __shfl_xor(m, 32, 64));
    float z = 0.f;
#pragma unroll
    for (int mi = 0; mi < 8; ++mi)
#pragma unroll
      for (int r = 0; r < 4; ++r) z += __expf(acc[mi][ni][r] + sb[ni] - m);
    z += __shfl_xor(z, 16, 64);
    z += __shfl_xor(z, 32, 64);
    if (lane < 16) {
      int n = nt * 256 + wn * 64 + ni * 16 + lane;
      if (n < 512) {
        size_t o = ((size_t)b * 512 + n) * JCH + jc;
        mglob[o] = m; zglob[o] = z;
      } else {
        locinv[((size_t)b * JCH + jc) * 512 + (n - 512)] = 1.0f / z;
      }
    }
  }
}

// ---------------- k_post: h1 GEMM | per-(b,hq) global max/denominator ----------------
__global__ __launch_bounds__(256) void k_post(const float* __restrict__ cvec, const float* __restrict__ W1,
                                              float* __restrict__ h1,
                                              const float* __restrict__ mglob, const float* __restrict__ zglob,
                                              float* __restrict__ Mh, float* __restrict__ Zr) {
  __shared__ __align__(16) char smem[8448];
  int blk = blockIdx.x, t = threadIdx.x;
  if (blk < 64) {
    int mt = blk >> 4, ntile = blk & 15;
    gemm64_direct(cvec, W1 + 1048576, h1, mt * 64, ntile * 64, smem);
  } else {
    int id = (blk - 64) * 256 + t;   // 0..2047
    int b = id >> 9, hq = id & 511;
    const float* mg = mglob + ((size_t)b * 512 + hq) * JCH;
    const float* zg = zglob + ((size_t)b * 512 + hq) * JCH;
    float m = -1e30f;
    for (int j = 0; j < JCH; ++j) m = fmaxf(m, mg[j]);
    float z = 0.f;
    for (int j = 0; j < JCH; ++j) z += zg[j] * __expf(mg[j] - m);
    Mh[id] = m;
    Zr[id] = 1.0f / z;
  }
}

// ---------------- per-(b,j) pooled scalars: att, loc, gate-dot (gelu fused) ----------------
__global__ __launch_bounds__(256) void k_chunk(const float* __restrict__ mglob, const float* __restrict__ zglob,
                                               const float* __restrict__ locinv,
                                               const float* __restrict__ Mh, const float* __restrict__ Zr,
                                               const float* __restrict__ h1, const float* __restrict__ qpart,
                                               const float* __restrict__ b1, const float* __restrict__ W2,
                                               float* __restrict__ abuf, float* __restrict__ lbuf,
                                               float* __restrict__ gbuf) {
  int bj = blockIdx.x, t = threadIdx.x;
  int b = bj >> 6, j = bj & 63;
  const float* mg = mglob + (size_t)b * 512 * JCH + j;   // stride JCH over hq
  const float* zg = zglob + (size_t)b * 512 * JCH + j;
  const float* lp = locinv + (size_t)bj * 512;
  const float* Mb = Mh + (size_t)b * 512;
  const float* Zb = Zr + (size_t)b * 512;
  float a = 0.f, l = 0.f, gsum = 0.f;
  for (int hq = t; hq < 512; hq += 256) {
    a += zg[(size_t)hq * JCH] * __expf(mg[(size_t)hq * JCH] - Mb[hq]) * Zb[hq];
    l += lp[hq];
  }
  const float* hp = h1 + (size_t)bj * HDIM;
  const float* qp = qpart + (size_t)b * HDIM;
  for (int n = t; n < HDIM; n += 256) {
    float x = hp[n] + qp[n] + b1[n];
    x = x * 0.5f * (1.0f + erff(x * 0.70710678118654752f));
    gsum += x * W2[n];
  }
#pragma unroll
  for (int o = 1; o < 64; o <<= 1) {
    a += __shfl_xor(a, o, 64); l += __shfl_xor(l, o, 64); gsum += __shfl_xor(gsum, o, 64);
  }
  __shared__ float ra[4], rl[4], rg[4];
  int wid = t >> 6, lane = t & 63;
  if (lane == 0) { ra[wid] = a; rl[wid] = l; rg[wid] = gsum; }
  __syncthreads();
  if (t == 0) {
    abuf[bj] = (ra[0] + ra[1] + ra[2] + ra[3]) * (1.0f / 65536.0f);
    lbuf[bj] = (rl[0] + rl[1] + rl[2] + rl[3]) * (1.0f / 512.0f);
    gbuf[bj] = rg[0] + rg[1] + rg[2] + rg[3];
  }
}

// ---------------- final: softmaxes over J, fuse, outputs ----------------
__global__ __launch_bounds__(64) void k_final(const float* __restrict__ abuf, const float* __restrict__ lbuf,
                                              const float* __restrict__ gbuf, const float* __restrict__ b2,
                                              float* __restrict__ out) {
  int b = blockIdx.x, t = threadIdx.x;   // 64 threads
  float a = abuf[b * 64 + t];
  float l = lbuf[b * 64 + t];
  float gt = gbuf[b * 64 + t] + b2[0];
  gt = 1.0f / (1.0f + __expf(-gt));
  float am = a, lm = l;
#pragma unroll
  for (int o = 1; o < 64; o <<= 1) { am = fmaxf(am, __shfl_xor(am, o, 64)); lm = fmaxf(lm, __shfl_xor(lm, o, 64)); }
  float ae = __expf(a - am), le = __expf(l - lm);
  float as_ = ae, ls_ = le;
#pragma unroll
  for (int o = 1; o < 64; o <<= 1) { as_ += __shfl_xor(as_, o, 64); ls_ += __shfl_xor(ls_, o, 64); }
  float gs = ae / as_, ls = le / ls_;
  float fu = gt * ls + (1.0f - gt) * gs;
  float fm = fu;
#pragma unroll
  for (int o = 1; o < 64; o <<= 1) fm = fmaxf(fm, __shfl_xor(fm, o, 64));
  float fe = __expf(fu - fm);
  float fs_ = fe;
#pragma unroll
  for (int o = 1; o < 64; o <<= 1) fs_ += __shfl_xor(fs_, o, 64);
  float fv = fe / fs_;
  out[b * 64 + t] = fv;
  out[256 + b * 64 + t] = ls;
  out[512 + b * 64 + t] = gs;
  float tot = fv;
#pragma unroll
  for (int o = 1; o < 64; o <<= 1) tot += __shfl_xor(tot, o, 64);
  if (t == 0) out[768 + b] = tot * (1.0f / 64.0f);
}

// ---------------- launcher ----------------
extern "C" void kernel_launch(void* const* d_in, const int* in_sizes, int n_in,
                              void* d_out, int out_size, void* d_ws, size_t ws_size,
                              hipStream_t stream) {
  const float* question = (const float*)d_in[0];
  const float* context  = (const float*)d_in[1];
  const float* Wq_l = (const float*)d_in[2];
  const float* bq_l = (const float*)d_in[3];
  const float* Wk_l = (const float*)d_in[4];
  const float* bk_l = (const float*)d_in[5];
  const float* Wq_g = (const float*)d_in[6];
  const float* bq_g = (const float*)d_in[7];
  const float* Wk_g = (const float*)d_in[8];
  const float* bk_g = (const float*)d_in[9];
  const float* ln_g = (const float*)d_in[10];
  const float* ln_b = (const float*)d_in[11];
  const float* W1   = (const float*)d_in[12];
  const float* b1   = (const float*)d_in[13];
  const float* W2   = (const float*)d_in[14];
  const float* b2   = (const float*)d_in[15];

  char* ws = (char*)d_ws;
  u16*   ctxb   = (u16*)(ws + 0);            // 67108864 B
  u16*   Ab     = (u16*)(ws + 67108864);     //  8388608 B
  float* qh     = (float*)(ws + 75497472);   //  1048576 B  [2][4][32][1024]
  float* sbias  = (float*)(ws + 76546048);   //    16384 B
  float* mglob  = (float*)(ws + 76562432);   //   524288 B  [4][512][64]  (transposed)
  float* zglob  = (float*)(ws + 77086720);   //   524288 B
  float* locinv = (float*)(ws + 77611008);   //   524288 B  [4][64][512]
  float* qvec   = (float*)(ws + 78135296);   //    16384 B
  float* cvec   = (float*)(ws + 78151680);   //  1048576 B  [256][1024]
  float* qpart  = (float*)(ws + 79200256);   //    16384 B
  float* h1     = (float*)(ws + 79216640);   //  1048576 B  [256][1024]
  float* Mh     = (float*)(ws + 80265216);   //     8192 B  [4][512]
  float* Zr     = (float*)(ws + 80273408);   //     8192 B
  float* abuf   = (float*)(ws + 80281600);   //     1024 B  [4][64]
  float* lbuf   = (float*)(ws + 80282624);   //     1024 B
  float* gbuf   = (float*)(ws + 80283648);   //     1024 B
  float* csum4  = (float*)(ws + 80284672);   //  4194304 B  [256][4][1024]

  hipLaunchKernelGGL(k_go, dim3(1093), dim3(256), 0, stream,
                     context, ctxb, csum4, question, Wq_g, Wq_l, qh, ln_g, ln_b, qvec, qpart);
  hipLaunchKernelGGL(k_mid, dim3(1040), dim3(256), 0, stream,
                     qh, Wk_g, Wk_l, bq_g, bq_l, Ab, bk_g, bk_l, sbias, qvec, W1, qpart,
                     csum4, ln_g, ln_b, cvec);
  hipLaunchKernelGGL(k_scores, dim3(512), dim3(512), 0, stream, ctxb, Ab, sbias, mglob, zglob, locinv);
  hipLaunchKernelGGL(k_post, dim3(72), dim3(256), 0, stream, cvec, W1, h1, mglob, zglob, Mh, Zr);
  hipLaunchKernelGGL(k_chunk, dim3(256), dim3(256), 0, stream, mglob, zglob, locinv, Mh, Zr, h1, qpart, b1, W2, abuf, lbuf, gbuf);
  hipLaunchKernelGGL(k_final, dim3(4), dim3(64), 0, stream, abuf, lbuf, gbuf, b2, (float*)d_out);
}